// Round 15
// baseline (277.153 us; speedup 1.0000x reference)
//
#include <hip/hip_runtime.h>
#include <hip/hip_bf16.h>

// Round 15: round-14 fused MFMA stack + two VALU/latency trims.
//  (1) All f32-pair -> bf16x2 packs via __float22bfloat162_rn (one
//      v_cvt_pk_bf16_f32 instead of 2 cvt + and/shl/or). RNE == f2bf pairs,
//      bit-identical output.
//  (2) Per-f loop reordered: all 4 B ds_read_b128 issued BEFORE the 24-perm
//      A-build, so LDS latency hides under the perm VALU work. Costs ~16
//      VGPR -- free, occupancy is LDS-capped at 4 blocks/CU (VGPR<=128 ok).
//  Everything else identical to round 14 (242us, absmax 4.9e-4).

#define CT 256

typedef unsigned int u32;
typedef short bf16x8 __attribute__((ext_vector_type(8)));
typedef float f32x4 __attribute__((ext_vector_type(4)));
typedef unsigned int u32x4 __attribute__((ext_vector_type(4)));

static __device__ __forceinline__ unsigned short f2bf(float f) {
    __hip_bfloat16 h = __float2bfloat16(f);
    return *reinterpret_cast<unsigned short*>(&h);
}
static __device__ __forceinline__ u32 pkbf(float a, float b) {
    __hip_bfloat162 h = __float22bfloat162_rn(make_float2(a, b));
    return *reinterpret_cast<u32*>(&h);
}

#define LSX   88
#define XCS   (44 * LSX)          // 3872
#define LS1   72
#define H1CS  (40 * LS1)          // 2880
#define H2CS  (36 * LS1)          // 2592
// ushort layout: sH1 [0,8640) | pad24 | sX [8664,20280) | pad16
#define SH1_OFF 0
#define SX_OFF  (3 * H1CS + 24)   // 8664 (x2B = 17328, 16B-aligned)
#define LDS_U   20296             // 40592 B -> 4 blocks/CU

// ---------------- weight pack ----------------
__global__ __launch_bounds__(128) void pack_weights(
    const float* __restrict__ w1, const float* __restrict__ w2,
    const float* __restrict__ w3, u32* __restrict__ tab)
{
    const int t = threadIdx.x;
    if (t < 105) {
        const float* w;
        if (t < 45)       w = w1 + t * 5;
        else if (t < 90)  w = w2 + (t - 45) * 5;
        else              w = w3 + (t - 90) * 5;
        tab[t * 3 + 0] = (u32)f2bf(w[0]) | ((u32)f2bf(w[1]) << 16);
        tab[t * 3 + 1] = (u32)f2bf(w[2]) | ((u32)f2bf(w[3]) << 16);
        tab[t * 3 + 2] = (u32)f2bf(w[4]);
    }
}

// ---------------- one fused conv stage (3 oc), LDS -> LDS ----------------
template<int TOFF, int LSI, int INCS, int LSO, int OUTCS, int RB2>
static __device__ __forceinline__ void conv_stage_mfma(
    const unsigned short* __restrict__ sin, unsigned short* __restrict__ sout,
    const u32* __restrict__ tab, const float* __restrict__ bias,
    int gy0m, int gx0m, int lanem, int g, int wid,
    const u32* selA, const u32* selB, bool interior)
{
    f32x4 acc[4][3];
    int rbv[4], cxv[4], rbi[4], baseb[4];
    bool val[4];
#pragma unroll
    for (int i = 0; i < 4; ++i) {
        const int t = wid + 4 * i;
        val[i] = (t < 15);
        const int tc = val[i] ? t : 0;
        cxv[i] = tc % 5;
        rbi[i] = tc / 5;
        rbv[i] = (rbi[i] == 0) ? 0 : (rbi[i] == 1 ? 16 : RB2);
        baseb[i] = ((rbv[i] + lanem) * LSI + 16 * cxv[i] + g * 8) * 2;
    }
#pragma unroll
    for (int oc = 0; oc < 3; ++oc) {
        const float bb = bias[oc];
#pragma unroll
        for (int i = 0; i < 4; ++i) acc[i][oc] = f32x4{bb, bb, bb, bb};
    }

#pragma unroll
    for (int f = 0; f < 15; ++f) {         // f = ic*5 + ky
        const int ic = f / 5, ky = f % 5;
        const int foff = (ic * INCS + ky * LSI) * 2;

        // (2) issue all B reads first: LDS latency hides under the A perms
        bf16x8 Bv[4];
#pragma unroll
        for (int i = 0; i < 4; ++i)
            if (val[i])
                Bv[i] = *reinterpret_cast<const bf16x8*>(
                    (const char*)sin + baseb[i] + foff);

        bf16x8 A[3];
#pragma unroll
        for (int oc = 0; oc < 3; ++oc) {
            const u32* wt = tab + (TOFF + (oc * 3 + ic) * 5 + ky) * 3;
            const u32 w01 = wt[0], w23 = wt[1], w4z = wt[2];
            u32x4 qv;
#pragma unroll
            for (int jj = 0; jj < 4; ++jj)
                qv[jj] = __builtin_amdgcn_perm(
                    __builtin_amdgcn_perm(w23, w01, selA[jj]), w4z, selB[jj]);
            A[oc] = __builtin_bit_cast(bf16x8, qv);
        }

#pragma unroll
        for (int i = 0; i < 4; ++i) {
            if (val[i]) {
#pragma unroll
                for (int oc = 0; oc < 3; ++oc)
                    acc[i][oc] = __builtin_amdgcn_mfma_f32_16x16x32_bf16(
                        A[oc], Bv[i], acc[i][oc], 0, 0, 0);
            }
        }
    }

    // epilogue: ReLU (+mask if boundary) -> bf16 (cvt_pk) -> LDS
#pragma unroll
    for (int i = 0; i < 4; ++i) {
        if (!val[i]) continue;
        const int colbase = 16 * cxv[i] + 4 * g;
        if (colbase >= LSO) continue;                    // stride overflow
        if (rbi[i] == 2 && lanem < 32 - RB2) continue;   // duplicate rows
        const int row = rbv[i] + lanem;
        const int Y = gy0m + row;
        const bool yok = (unsigned)Y < 256u;
#pragma unroll
        for (int oc = 0; oc < 3; ++oc) {
            float v[4];
#pragma unroll
            for (int p = 0; p < 4; ++p) {
                float rv = fmaxf(acc[i][oc][p], 0.f);
                if (!interior) {
                    const bool ok = yok & ((unsigned)(gx0m + colbase + p) < 256u);
                    rv = ok ? rv : 0.f;
                }
                v[p] = rv;
            }
            *reinterpret_cast<uint2*>(
                sout + oc * OUTCS + row * LSO + colbase) =
                make_uint2(pkbf(v[0], v[1]), pkbf(v[2], v[3]));
        }
    }
}

// ---------------- fused kernel ----------------
__global__ __launch_bounds__(CT) void fused_mfma(
    const float* __restrict__ x,
    const float* __restrict__ b1, const float* __restrict__ b2,
    const float* __restrict__ b3,
    const u32* __restrict__ tab, float* __restrict__ feat)
{
    const int pos = blockIdx.x;            // 0..31
    const int b   = blockIdx.y;            // image
    const int tx = pos & 3, ty = pos >> 2;
    const int tid = threadIdx.x;
    const int lane = tid & 63, wid = tid >> 6;
    const int lanem = lane & 15, g = lane >> 4;

    __shared__ __align__(16) unsigned short lds_u[LDS_U];   // 40592 B
    unsigned short* sH1 = lds_u + SH1_OFF;
    unsigned short* sX  = lds_u + SX_OFF;
    unsigned short* sH2 = sX;               // alias (sX dead after conv1)

    const int gy0 = ty * 32, gx0 = tx * 64;
    const bool interior = (tx >= 1) & (tx <= 2) & (ty >= 1) & (ty <= 6);

    // ---- perm selectors (rounds 10-14 verified) ----
    u32 selA[4], selB[4];
#pragma unroll
    for (int jj = 0; jj < 4; ++jj) {
        u32 a = 0, bs = 0;
#pragma unroll
        for (int byt = 0; byt < 4; ++byt) {
            const int j = 2 * jj + (byt >> 1);
            const int d = g * 8 + j - lanem;
            const int h = byt & 1;
            u32 av, bv;
            if      (d == 0) av = 0 + h;
            else if (d == 1) av = 2 + h;
            else if (d == 2) av = 4 + h;
            else if (d == 3) av = 6 + h;
            else             av = 0;
            if      (d == 4)           bv = 0 + h;   // w4
            else if (d >= 0 && d < 4)  bv = 4 + byt; // keep t1 byte
            else                       bv = 2 + h;   // zero
            a  |= av << (8 * byt);
            bs |= bv << (8 * byt);
        }
        selA[jj] = a; selB[jj] = bs;
    }

    // ---- zero the tail pads ----
    {
        u32* w32 = reinterpret_cast<u32*>(lds_u);
        if (tid < 12)      w32[(3 * H1CS) / 2 + tid] = 0;
        else if (tid < 20) w32[(SX_OFF + 3 * XCS) / 2 + (tid - 12)] = 0;
    }

    // ---- stage x: 44 rows x 88 cols x 3 ch, bf16 ----
    if (interior) {
        for (int p = tid; p < 44 * 44; p += CT) {
            const int r = p / 44;
            const int k = p - r * 44;
            const int gy = gy0 - 6 + r;
            const int gx = gx0 - 6 + 2 * k;
#pragma unroll
            for (int c = 0; c < 3; ++c) {
                const float2 v = *reinterpret_cast<const float2*>(
                    x + (((size_t)b * 3 + c) * 256 + gy) * 256 + gx);
                *reinterpret_cast<u32*>(&sX[c * XCS + r * LSX + 2 * k]) =
                    pkbf(v.x, v.y);
            }
        }
    } else {
        for (int p = tid; p < 44 * 44; p += CT) {
            const int r = p / 44;
            const int k = p - r * 44;
            const int gy = gy0 - 6 + r;
            const int gx = gx0 - 6 + 2 * k;
            const bool yok  = ((unsigned)gy < 256u) & (k < 38);
            const bool full = yok & (gx >= 0) & (gx + 1 < 256);
#pragma unroll
            for (int c = 0; c < 3; ++c) {
                u32 packed = 0;
                if (yok) {
                    const float* src = x + (((size_t)b * 3 + c) * 256 + gy) * 256;
                    float vx = 0.f, vy = 0.f;
                    if (full) {
                        const float2 v = *reinterpret_cast<const float2*>(src + gx);
                        vx = v.x; vy = v.y;
                    } else {
                        if ((unsigned)gx < 256u)       vx = src[gx];
                        if ((unsigned)(gx + 1) < 256u) vy = src[gx + 1];
                    }
                    packed = pkbf(vx, vy);
                }
                *reinterpret_cast<u32*>(&sX[c * XCS + r * LSX + 2 * k]) = packed;
            }
        }
    }
    __syncthreads();

    // ---- conv1: sX(88) -> sH1(72), origin (gy0-4, gx0-4) ----
    conv_stage_mfma<0, LSX, XCS, LS1, H1CS, 24>(sX, sH1, tab, b1,
        gy0 - 4, gx0 - 4, lanem, g, wid, selA, selB, interior);
    __syncthreads();

    // ---- conv2: sH1(72) -> sH2(72), origin (gy0-2, gx0-2) ----
    conv_stage_mfma<45, LS1, H1CS, LS1, H2CS, 20>(sH1, sH2, tab, b2,
        gy0 - 2, gx0 - 2, lanem, g, wid, selA, selB, interior);
    __syncthreads();

    // ---- conv3 + patch-mean: sH2 -> feat ----
    {
        const float bb = b3[0];
        f32x4 a3[2] = {f32x4{bb, bb, bb, bb}, f32x4{bb, bb, bb, bb}};
        int base_s[2];
#pragma unroll
        for (int s = 0; s < 2; ++s)
            base_s[s] = ((s * 16 + lanem) * LS1 + 16 * wid + g * 8) * 2;

#pragma unroll
        for (int f = 0; f < 15; ++f) {
            const int ic = f / 5, ky = f % 5;
            const int foff = (ic * H2CS + ky * LS1) * 2;
            bf16x8 B0 = *reinterpret_cast<const bf16x8*>(
                (const char*)sH2 + base_s[0] + foff);
            bf16x8 B1 = *reinterpret_cast<const bf16x8*>(
                (const char*)sH2 + base_s[1] + foff);
            const u32* wt = tab + (90 + f) * 3;
            const u32 w01 = wt[0], w23 = wt[1], w4z = wt[2];
            u32x4 qv;
#pragma unroll
            for (int jj = 0; jj < 4; ++jj)
                qv[jj] = __builtin_amdgcn_perm(
                    __builtin_amdgcn_perm(w23, w01, selA[jj]), w4z, selB[jj]);
            const bf16x8 A = __builtin_bit_cast(bf16x8, qv);
            a3[0] = __builtin_amdgcn_mfma_f32_16x16x32_bf16(A, B0, a3[0], 0, 0, 0);
            a3[1] = __builtin_amdgcn_mfma_f32_16x16x32_bf16(A, B1, a3[1], 0, 0, 0);
        }
#pragma unroll
        for (int s = 0; s < 2; ++s) {
            float sum = fmaxf(a3[s][0], 0.f) + fmaxf(a3[s][1], 0.f)
                      + fmaxf(a3[s][2], 0.f) + fmaxf(a3[s][3], 0.f);
            sum += __shfl_xor(sum, 1, 64);
            sum += __shfl_xor(sum, 2, 64);
            sum += __shfl_xor(sum, 4, 64);
            sum += __shfl_xor(sum, 8, 64);
            sum += __shfl_xor(sum, 16, 64);
            sum += __shfl_xor(sum, 32, 64);
            if (lane == 0) {
                const int j = ty * 2 + s, i2 = tx * 4 + wid;
                feat[(size_t)b * 256 + j * 16 + i2] = sum * (1.f / 256.f);
            }
        }
    }
}

// ---------------- MLP head ----------------
__global__ __launch_bounds__(64) void mlp_head(
    const float* __restrict__ feat,
    const float* __restrict__ wl1, const float* __restrict__ bl1,
    const float* __restrict__ wl2, const float* __restrict__ bl2,
    float* __restrict__ out)
{
    const int b = blockIdx.x;
    const int t = threadIdx.x;

    __shared__ float sF[256];
    __shared__ float sE[64];
    __shared__ float sL[8];
    __shared__ float sXx[8];

    for (int i = t; i < 256; i += 64) sF[i] = feat[(size_t)b * 256 + i];
    __syncthreads();

    float acc = bl1[t];
    for (int k = 0; k < 256; ++k) acc = fmaf(sF[k], wl1[t * 256 + k], acc);
    sE[t] = acc;
    __syncthreads();

    if (t < 8) {
        float l = bl2[t];
#pragma unroll
        for (int k = 0; k < 64; ++k) l = fmaf(sE[k], wl2[t * 64 + k], l);
        sL[t] = l;
    }
    __syncthreads();

    if (t < 8) {
        float m = sL[0];
#pragma unroll
        for (int k = 1; k < 8; ++k) m = fmaxf(m, sL[k]);
        sXx[t] = __expf(sL[t] - m);
    }
    __syncthreads();

    if (t < 8) {
        float sum = 0.f;
#pragma unroll
        for (int k = 0; k < 8; ++k) sum += sXx[k];
        out[(size_t)b * 8 + t] = sXx[t] / sum;
    }
}

// ---------------- scalar fused fallback (round-3) ----------------
#define NTHREADS 512

template<int ICn, int OCn, int OW, int OH, int IS, int ICSZ, int OS, int OCSZ, bool MASK>
__device__ __forceinline__ void conv5x5(
    const float* __restrict__ sin, float* __restrict__ sout,
    const float* __restrict__ w, const float* __restrict__ bias,
    int gy0, int gx0, int tid)
{
    constexpr int QX = OW / 4;
    constexpr int RY = OH / 2;
    constexpr int TASKS = QX * RY;
    if (tid < TASKS) {
        const int ry = tid / QX;
        const int qx = tid - ry * QX;
        const int y0 = ry * 2, x0 = qx * 4;
        float acc[2][OCn][4];
#pragma unroll
        for (int c = 0; c < OCn; ++c) {
            const float bb = bias[c];
#pragma unroll
            for (int p = 0; p < 4; ++p) { acc[0][c][p] = bb; acc[1][c][p] = bb; }
        }
#pragma unroll
        for (int ic = 0; ic < ICn; ++ic) {
            const float* base = sin + ic * ICSZ + y0 * IS + x0;
#pragma unroll
            for (int r = 0; r < 6; ++r) {
                const float4 a4 = *reinterpret_cast<const float4*>(base + r * IS);
                const float4 b4 = *reinterpret_cast<const float4*>(base + r * IS + 4);
                const float v[8] = {a4.x, a4.y, a4.z, a4.w, b4.x, b4.y, b4.z, b4.w};
#pragma unroll
                for (int kx = 0; kx < 5; ++kx)
#pragma unroll
                    for (int c = 0; c < OCn; ++c) {
                        if (r < 5) {
                            const float wv = w[((c * ICn + ic) * 5 + r) * 5 + kx];
#pragma unroll
                            for (int p = 0; p < 4; ++p)
                                acc[0][c][p] = fmaf(v[p + kx], wv, acc[0][c][p]);
                        }
                        if (r >= 1) {
                            const float wv = w[((c * ICn + ic) * 5 + (r - 1)) * 5 + kx];
#pragma unroll
                            for (int p = 0; p < 4; ++p)
                                acc[1][c][p] = fmaf(v[p + kx], wv, acc[1][c][p]);
                        }
                    }
            }
        }
#pragma unroll
        for (int rr = 0; rr < 2; ++rr) {
            const int gy = gy0 + y0 + rr;
#pragma unroll
            for (int c = 0; c < OCn; ++c) {
                float o[4];
#pragma unroll
                for (int p = 0; p < 4; ++p) {
                    float rv = fmaxf(acc[rr][c][p], 0.f);
                    if (MASK) {
                        const int gx = gx0 + x0 + p;
                        const bool ok = ((unsigned)gy < 256u) & ((unsigned)gx < 256u);
                        rv = ok ? rv : 0.f;
                    }
                    o[p] = rv;
                }
                *reinterpret_cast<float4*>(&sout[c * OCSZ + (y0 + rr) * OS + x0]) =
                    make_float4(o[0], o[1], o[2], o[3]);
            }
        }
    }
}

__global__ __launch_bounds__(NTHREADS) void fused_conv_feat(
    const float* __restrict__ x,
    const float* __restrict__ w1, const float* __restrict__ b1,
    const float* __restrict__ w2, const float* __restrict__ b2,
    const float* __restrict__ w3, const float* __restrict__ b3,
    float* __restrict__ feat)
{
    const int tile = blockIdx.x;
    const int b    = blockIdx.y;
    const int tx   = tile & 3, ty = tile >> 2;
    const int tid  = threadIdx.x;

    __shared__ __align__(16) float lds[10032 + 9120];
    float* sIn = lds;
    float* sH1 = lds + 10032;
    float* sH2 = lds;
    float* sH3 = lds + 10032;

    const int gy0s = ty * 32 - 6, gx0s = tx * 64 - 6;
    for (int i = tid; i < 3 * 44 * 38; i += NTHREADS) {
        const int c   = i / 1672;
        const int rem = i - c * 1672;
        const int r   = rem / 38;
        const int k   = rem - r * 38;
        const int gy = gy0s + r, gx = gx0s + 2 * k;
        float2 v = make_float2(0.f, 0.f);
        if ((unsigned)gy < 256u) {
            const float* src = x + (((size_t)b * 3 + c) * 256 + gy) * 256;
            if (gx >= 0 && gx + 1 < 256) {
                v = *reinterpret_cast<const float2*>(src + gx);
            } else {
                if ((unsigned)gx < 256u)       v.x = src[gx];
                if ((unsigned)(gx + 1) < 256u) v.y = src[gx + 1];
            }
        }
        *reinterpret_cast<float2*>(&sIn[c * 3344 + r * 76 + 2 * k]) = v;
    }
    __syncthreads();

    conv5x5<3, 3, 72, 40, 76, 3344, 76, 3040, true>(sIn, sH1, w1, b1,
                                                    ty * 32 - 4, tx * 64 - 4, tid);
    __syncthreads();
    conv5x5<3, 3, 68, 36, 76, 3040, 76, 2736, true>(sH1, sH2, w2, b2,
                                                    ty * 32 - 2, tx * 64 - 2, tid);
    __syncthreads();
    conv5x5<3, 1, 64, 32, 76, 2736, 64, 2048, false>(sH2, sH3, w3, b3, 0, 0, tid);
    __syncthreads();

    const int wv   = tid >> 6;
    const int lane = tid & 63;
    const int py = wv >> 2, px = wv & 3;
    float s = 0.f;
#pragma unroll
    for (int k = 0; k < 4; ++k) {
        const int idx = lane + k * 64;
        const int r = idx >> 4, cc = idx & 15;
        s += sH3[(py * 16 + r) * 64 + px * 16 + cc];
    }
#pragma unroll
    for (int off = 32; off > 0; off >>= 1) s += __shfl_down(s, off, 64);
    if (lane == 0) {
        const int j = ty * 2 + py, i = tx * 4 + px;
        feat[(size_t)b * 256 + j * 16 + i] = s * (1.f / 256.f);
    }
}

extern "C" void kernel_launch(void* const* d_in, const int* in_sizes, int n_in,
                              void* d_out, int out_size, void* d_ws, size_t ws_size,
                              hipStream_t stream) {
    const float* x   = (const float*)d_in[0];
    const float* w1  = (const float*)d_in[1];
    const float* b1  = (const float*)d_in[2];
    const float* w2  = (const float*)d_in[3];
    const float* b2  = (const float*)d_in[4];
    const float* w3  = (const float*)d_in[5];
    const float* b3  = (const float*)d_in[6];
    const float* wl1 = (const float*)d_in[7];
    const float* bl1 = (const float*)d_in[8];
    const float* wl2 = (const float*)d_in[9];
    const float* bl2 = (const float*)d_in[10];
    float* out  = (float*)d_out;

    const size_t FEAT_B = 256u * 256u * 4u;   // 262144
    const size_t TAB_B  = 4096;
    float* feat = (float*)d_ws;

    if (ws_size >= FEAT_B + TAB_B) {
        u32* wtab = (u32*)((char*)d_ws + FEAT_B);
        pack_weights<<<1, 128, 0, stream>>>(w1, w2, w3, wtab);
        dim3 g(32, 256);
        fused_mfma<<<g, CT, 0, stream>>>(x, b1, b2, b3, wtab, feat);
    } else {
        dim3 g1(32, 256);
        fused_conv_feat<<<g1, NTHREADS, 0, stream>>>(x, w1, b1, w2, b2, w3, b3, feat);
    }
    mlp_head<<<256, 64, 0, stream>>>(feat, wl1, bl1, wl2, bl2, out);
}

// Round 16
// 242.437 us; speedup vs baseline: 1.1432x; 1.1432x over previous
//
#include <hip/hip_runtime.h>
#include <hip/hip_bf16.h>

// Round 16: EXACT revert to round-14 structure (242us, best) with ONLY the
// cvt_pk packing kept from round 15 (isolated A/B).
//  - B ds_read back INSIDE the per-i MFMA loop (compiler schedules fine-
//    grained lgkmcnt; round-15's manual prefetch-all-B broke that, -15%).
//  - f32-pair -> bf16x2 via __float22bfloat162_rn (v_cvt_pk_bf16_f32), RNE
//    == __float2bfloat16 pairs -> bit-identical output.
//  Everything else == round 14.

#define CT 256

typedef unsigned int u32;
typedef short bf16x8 __attribute__((ext_vector_type(8)));
typedef float f32x4 __attribute__((ext_vector_type(4)));
typedef unsigned int u32x4 __attribute__((ext_vector_type(4)));

static __device__ __forceinline__ unsigned short f2bf(float f) {
    __hip_bfloat16 h = __float2bfloat16(f);
    return *reinterpret_cast<unsigned short*>(&h);
}
static __device__ __forceinline__ u32 pkbf(float a, float b) {
    __hip_bfloat162 h = __float22bfloat162_rn(make_float2(a, b));
    return *reinterpret_cast<u32*>(&h);
}

#define LSX   88
#define XCS   (44 * LSX)          // 3872
#define LS1   72
#define H1CS  (40 * LS1)          // 2880
#define H2CS  (36 * LS1)          // 2592
// ushort layout: sH1 [0,8640) | pad24 | sX [8664,20280) | pad16
#define SH1_OFF 0
#define SX_OFF  (3 * H1CS + 24)   // 8664 (x2B = 17328, 16B-aligned)
#define LDS_U   20296             // 40592 B -> 4 blocks/CU

// ---------------- weight pack ----------------
__global__ __launch_bounds__(128) void pack_weights(
    const float* __restrict__ w1, const float* __restrict__ w2,
    const float* __restrict__ w3, u32* __restrict__ tab)
{
    const int t = threadIdx.x;
    if (t < 105) {
        const float* w;
        if (t < 45)       w = w1 + t * 5;
        else if (t < 90)  w = w2 + (t - 45) * 5;
        else              w = w3 + (t - 90) * 5;
        tab[t * 3 + 0] = (u32)f2bf(w[0]) | ((u32)f2bf(w[1]) << 16);
        tab[t * 3 + 1] = (u32)f2bf(w[2]) | ((u32)f2bf(w[3]) << 16);
        tab[t * 3 + 2] = (u32)f2bf(w[4]);
    }
}

// ---------------- one fused conv stage (3 oc), LDS -> LDS ----------------
template<int TOFF, int LSI, int INCS, int LSO, int OUTCS, int RB2>
static __device__ __forceinline__ void conv_stage_mfma(
    const unsigned short* __restrict__ sin, unsigned short* __restrict__ sout,
    const u32* __restrict__ tab, const float* __restrict__ bias,
    int gy0m, int gx0m, int lanem, int g, int wid,
    const u32* selA, const u32* selB, bool interior)
{
    f32x4 acc[4][3];
    int rbv[4], cxv[4], rbi[4], baseb[4];
    bool val[4];
#pragma unroll
    for (int i = 0; i < 4; ++i) {
        const int t = wid + 4 * i;
        val[i] = (t < 15);
        const int tc = val[i] ? t : 0;
        cxv[i] = tc % 5;
        rbi[i] = tc / 5;
        rbv[i] = (rbi[i] == 0) ? 0 : (rbi[i] == 1 ? 16 : RB2);
        baseb[i] = ((rbv[i] + lanem) * LSI + 16 * cxv[i] + g * 8) * 2;
    }
#pragma unroll
    for (int oc = 0; oc < 3; ++oc) {
        const float bb = bias[oc];
#pragma unroll
        for (int i = 0; i < 4; ++i) acc[i][oc] = f32x4{bb, bb, bb, bb};
    }

#pragma unroll
    for (int f = 0; f < 15; ++f) {         // f = ic*5 + ky
        const int ic = f / 5, ky = f % 5;
        bf16x8 A[3];
#pragma unroll
        for (int oc = 0; oc < 3; ++oc) {
            const u32* wt = tab + (TOFF + (oc * 3 + ic) * 5 + ky) * 3;
            const u32 w01 = wt[0], w23 = wt[1], w4z = wt[2];
            u32x4 qv;
#pragma unroll
            for (int jj = 0; jj < 4; ++jj)
                qv[jj] = __builtin_amdgcn_perm(
                    __builtin_amdgcn_perm(w23, w01, selA[jj]), w4z, selB[jj]);
            A[oc] = __builtin_bit_cast(bf16x8, qv);
        }
        const int foff = (ic * INCS + ky * LSI) * 2;
#pragma unroll
        for (int i = 0; i < 4; ++i) {
            if (val[i]) {
                const bf16x8 B = *reinterpret_cast<const bf16x8*>(
                    (const char*)sin + baseb[i] + foff);
#pragma unroll
                for (int oc = 0; oc < 3; ++oc)
                    acc[i][oc] = __builtin_amdgcn_mfma_f32_16x16x32_bf16(
                        A[oc], B, acc[i][oc], 0, 0, 0);
            }
        }
    }

    // epilogue: ReLU (+mask if boundary) -> bf16 (cvt_pk) -> LDS
#pragma unroll
    for (int i = 0; i < 4; ++i) {
        if (!val[i]) continue;
        const int colbase = 16 * cxv[i] + 4 * g;
        if (colbase >= LSO) continue;                    // stride overflow
        if (rbi[i] == 2 && lanem < 32 - RB2) continue;   // duplicate rows
        const int row = rbv[i] + lanem;
        const int Y = gy0m + row;
        const bool yok = (unsigned)Y < 256u;
#pragma unroll
        for (int oc = 0; oc < 3; ++oc) {
            float v[4];
#pragma unroll
            for (int p = 0; p < 4; ++p) {
                float rv = fmaxf(acc[i][oc][p], 0.f);
                if (!interior) {
                    const bool ok = yok & ((unsigned)(gx0m + colbase + p) < 256u);
                    rv = ok ? rv : 0.f;
                }
                v[p] = rv;
            }
            *reinterpret_cast<uint2*>(
                sout + oc * OUTCS + row * LSO + colbase) =
                make_uint2(pkbf(v[0], v[1]), pkbf(v[2], v[3]));
        }
    }
}

// ---------------- fused kernel ----------------
__global__ __launch_bounds__(CT) void fused_mfma(
    const float* __restrict__ x,
    const float* __restrict__ b1, const float* __restrict__ b2,
    const float* __restrict__ b3,
    const u32* __restrict__ tab, float* __restrict__ feat)
{
    const int pos = blockIdx.x;            // 0..31
    const int b   = blockIdx.y;            // image
    const int tx = pos & 3, ty = pos >> 2;
    const int tid = threadIdx.x;
    const int lane = tid & 63, wid = tid >> 6;
    const int lanem = lane & 15, g = lane >> 4;

    __shared__ __align__(16) unsigned short lds_u[LDS_U];   // 40592 B
    unsigned short* sH1 = lds_u + SH1_OFF;
    unsigned short* sX  = lds_u + SX_OFF;
    unsigned short* sH2 = sX;               // alias (sX dead after conv1)

    const int gy0 = ty * 32, gx0 = tx * 64;
    const bool interior = (tx >= 1) & (tx <= 2) & (ty >= 1) & (ty <= 6);

    // ---- perm selectors (rounds 10-14 verified) ----
    u32 selA[4], selB[4];
#pragma unroll
    for (int jj = 0; jj < 4; ++jj) {
        u32 a = 0, bs = 0;
#pragma unroll
        for (int byt = 0; byt < 4; ++byt) {
            const int j = 2 * jj + (byt >> 1);
            const int d = g * 8 + j - lanem;
            const int h = byt & 1;
            u32 av, bv;
            if      (d == 0) av = 0 + h;
            else if (d == 1) av = 2 + h;
            else if (d == 2) av = 4 + h;
            else if (d == 3) av = 6 + h;
            else             av = 0;
            if      (d == 4)           bv = 0 + h;   // w4
            else if (d >= 0 && d < 4)  bv = 4 + byt; // keep t1 byte
            else                       bv = 2 + h;   // zero
            a  |= av << (8 * byt);
            bs |= bv << (8 * byt);
        }
        selA[jj] = a; selB[jj] = bs;
    }

    // ---- zero the tail pads ----
    {
        u32* w32 = reinterpret_cast<u32*>(lds_u);
        if (tid < 12)      w32[(3 * H1CS) / 2 + tid] = 0;
        else if (tid < 20) w32[(SX_OFF + 3 * XCS) / 2 + (tid - 12)] = 0;
    }

    // ---- stage x: 44 rows x 88 cols x 3 ch, bf16 ----
    if (interior) {
        for (int p = tid; p < 44 * 44; p += CT) {
            const int r = p / 44;
            const int k = p - r * 44;
            const int gy = gy0 - 6 + r;
            const int gx = gx0 - 6 + 2 * k;
#pragma unroll
            for (int c = 0; c < 3; ++c) {
                const float2 v = *reinterpret_cast<const float2*>(
                    x + (((size_t)b * 3 + c) * 256 + gy) * 256 + gx);
                *reinterpret_cast<u32*>(&sX[c * XCS + r * LSX + 2 * k]) =
                    pkbf(v.x, v.y);
            }
        }
    } else {
        for (int p = tid; p < 44 * 44; p += CT) {
            const int r = p / 44;
            const int k = p - r * 44;
            const int gy = gy0 - 6 + r;
            const int gx = gx0 - 6 + 2 * k;
            const bool yok  = ((unsigned)gy < 256u) & (k < 38);
            const bool full = yok & (gx >= 0) & (gx + 1 < 256);
#pragma unroll
            for (int c = 0; c < 3; ++c) {
                u32 packed = 0;
                if (yok) {
                    const float* src = x + (((size_t)b * 3 + c) * 256 + gy) * 256;
                    float vx = 0.f, vy = 0.f;
                    if (full) {
                        const float2 v = *reinterpret_cast<const float2*>(src + gx);
                        vx = v.x; vy = v.y;
                    } else {
                        if ((unsigned)gx < 256u)       vx = src[gx];
                        if ((unsigned)(gx + 1) < 256u) vy = src[gx + 1];
                    }
                    packed = pkbf(vx, vy);
                }
                *reinterpret_cast<u32*>(&sX[c * XCS + r * LSX + 2 * k]) = packed;
            }
        }
    }
    __syncthreads();

    // ---- conv1: sX(88) -> sH1(72), origin (gy0-4, gx0-4) ----
    conv_stage_mfma<0, LSX, XCS, LS1, H1CS, 24>(sX, sH1, tab, b1,
        gy0 - 4, gx0 - 4, lanem, g, wid, selA, selB, interior);
    __syncthreads();

    // ---- conv2: sH1(72) -> sH2(72), origin (gy0-2, gx0-2) ----
    conv_stage_mfma<45, LS1, H1CS, LS1, H2CS, 20>(sH1, sH2, tab, b2,
        gy0 - 2, gx0 - 2, lanem, g, wid, selA, selB, interior);
    __syncthreads();

    // ---- conv3 + patch-mean: sH2 -> feat; tiles (cx=wid, rb in {0,16}) ----
    {
        const float bb = b3[0];
        f32x4 a3[2] = {f32x4{bb, bb, bb, bb}, f32x4{bb, bb, bb, bb}};
        int base_s[2];
#pragma unroll
        for (int s = 0; s < 2; ++s)
            base_s[s] = ((s * 16 + lanem) * LS1 + 16 * wid + g * 8) * 2;

#pragma unroll
        for (int f = 0; f < 15; ++f) {
            const int ic = f / 5, ky = f % 5;
            const u32* wt = tab + (90 + f) * 3;
            const u32 w01 = wt[0], w23 = wt[1], w4z = wt[2];
            u32x4 qv;
#pragma unroll
            for (int jj = 0; jj < 4; ++jj)
                qv[jj] = __builtin_amdgcn_perm(
                    __builtin_amdgcn_perm(w23, w01, selA[jj]), w4z, selB[jj]);
            const bf16x8 A = __builtin_bit_cast(bf16x8, qv);
            const int foff = (ic * H2CS + ky * LS1) * 2;
#pragma unroll
            for (int s = 0; s < 2; ++s) {
                const bf16x8 B = *reinterpret_cast<const bf16x8*>(
                    (const char*)sH2 + base_s[s] + foff);
                a3[s] = __builtin_amdgcn_mfma_f32_16x16x32_bf16(A, B, a3[s], 0, 0, 0);
            }
        }
#pragma unroll
        for (int s = 0; s < 2; ++s) {
            float sum = fmaxf(a3[s][0], 0.f) + fmaxf(a3[s][1], 0.f)
                      + fmaxf(a3[s][2], 0.f) + fmaxf(a3[s][3], 0.f);
            sum += __shfl_xor(sum, 1, 64);
            sum += __shfl_xor(sum, 2, 64);
            sum += __shfl_xor(sum, 4, 64);
            sum += __shfl_xor(sum, 8, 64);
            sum += __shfl_xor(sum, 16, 64);
            sum += __shfl_xor(sum, 32, 64);
            if (lane == 0) {
                const int j = ty * 2 + s, i2 = tx * 4 + wid;
                feat[(size_t)b * 256 + j * 16 + i2] = sum * (1.f / 256.f);
            }
        }
    }
}

// ---------------- MLP head ----------------
__global__ __launch_bounds__(64) void mlp_head(
    const float* __restrict__ feat,
    const float* __restrict__ wl1, const float* __restrict__ bl1,
    const float* __restrict__ wl2, const float* __restrict__ bl2,
    float* __restrict__ out)
{
    const int b = blockIdx.x;
    const int t = threadIdx.x;

    __shared__ float sF[256];
    __shared__ float sE[64];
    __shared__ float sL[8];
    __shared__ float sXx[8];

    for (int i = t; i < 256; i += 64) sF[i] = feat[(size_t)b * 256 + i];
    __syncthreads();

    float acc = bl1[t];
    for (int k = 0; k < 256; ++k) acc = fmaf(sF[k], wl1[t * 256 + k], acc);
    sE[t] = acc;
    __syncthreads();

    if (t < 8) {
        float l = bl2[t];
#pragma unroll
        for (int k = 0; k < 64; ++k) l = fmaf(sE[k], wl2[t * 64 + k], l);
        sL[t] = l;
    }
    __syncthreads();

    if (t < 8) {
        float m = sL[0];
#pragma unroll
        for (int k = 1; k < 8; ++k) m = fmaxf(m, sL[k]);
        sXx[t] = __expf(sL[t] - m);
    }
    __syncthreads();

    if (t < 8) {
        float sum = 0.f;
#pragma unroll
        for (int k = 0; k < 8; ++k) sum += sXx[k];
        out[(size_t)b * 8 + t] = sXx[t] / sum;
    }
}

// ---------------- scalar fused fallback (round-3) ----------------
#define NTHREADS 512

template<int ICn, int OCn, int OW, int OH, int IS, int ICSZ, int OS, int OCSZ, bool MASK>
__device__ __forceinline__ void conv5x5(
    const float* __restrict__ sin, float* __restrict__ sout,
    const float* __restrict__ w, const float* __restrict__ bias,
    int gy0, int gx0, int tid)
{
    constexpr int QX = OW / 4;
    constexpr int RY = OH / 2;
    constexpr int TASKS = QX * RY;
    if (tid < TASKS) {
        const int ry = tid / QX;
        const int qx = tid - ry * QX;
        const int y0 = ry * 2, x0 = qx * 4;
        float acc[2][OCn][4];
#pragma unroll
        for (int c = 0; c < OCn; ++c) {
            const float bb = bias[c];
#pragma unroll
            for (int p = 0; p < 4; ++p) { acc[0][c][p] = bb; acc[1][c][p] = bb; }
        }
#pragma unroll
        for (int ic = 0; ic < ICn; ++ic) {
            const float* base = sin + ic * ICSZ + y0 * IS + x0;
#pragma unroll
            for (int r = 0; r < 6; ++r) {
                const float4 a4 = *reinterpret_cast<const float4*>(base + r * IS);
                const float4 b4 = *reinterpret_cast<const float4*>(base + r * IS + 4);
                const float v[8] = {a4.x, a4.y, a4.z, a4.w, b4.x, b4.y, b4.z, b4.w};
#pragma unroll
                for (int kx = 0; kx < 5; ++kx)
#pragma unroll
                    for (int c = 0; c < OCn; ++c) {
                        if (r < 5) {
                            const float wv = w[((c * ICn + ic) * 5 + r) * 5 + kx];
#pragma unroll
                            for (int p = 0; p < 4; ++p)
                                acc[0][c][p] = fmaf(v[p + kx], wv, acc[0][c][p]);
                        }
                        if (r >= 1) {
                            const float wv = w[((c * ICn + ic) * 5 + (r - 1)) * 5 + kx];
#pragma unroll
                            for (int p = 0; p < 4; ++p)
                                acc[1][c][p] = fmaf(v[p + kx], wv, acc[1][c][p]);
                        }
                    }
            }
        }
#pragma unroll
        for (int rr = 0; rr < 2; ++rr) {
            const int gy = gy0 + y0 + rr;
#pragma unroll
            for (int c = 0; c < OCn; ++c) {
                float o[4];
#pragma unroll
                for (int p = 0; p < 4; ++p) {
                    float rv = fmaxf(acc[rr][c][p], 0.f);
                    if (MASK) {
                        const int gx = gx0 + x0 + p;
                        const bool ok = ((unsigned)gy < 256u) & ((unsigned)gx < 256u);
                        rv = ok ? rv : 0.f;
                    }
                    o[p] = rv;
                }
                *reinterpret_cast<float4*>(&sout[c * OCSZ + (y0 + rr) * OS + x0]) =
                    make_float4(o[0], o[1], o[2], o[3]);
            }
        }
    }
}

__global__ __launch_bounds__(NTHREADS) void fused_conv_feat(
    const float* __restrict__ x,
    const float* __restrict__ w1, const float* __restrict__ b1,
    const float* __restrict__ w2, const float* __restrict__ b2,
    const float* __restrict__ w3, const float* __restrict__ b3,
    float* __restrict__ feat)
{
    const int tile = blockIdx.x;
    const int b    = blockIdx.y;
    const int tx   = tile & 3, ty = tile >> 2;
    const int tid  = threadIdx.x;

    __shared__ __align__(16) float lds[10032 + 9120];
    float* sIn = lds;
    float* sH1 = lds + 10032;
    float* sH2 = lds;
    float* sH3 = lds + 10032;

    const int gy0s = ty * 32 - 6, gx0s = tx * 64 - 6;
    for (int i = tid; i < 3 * 44 * 38; i += NTHREADS) {
        const int c   = i / 1672;
        const int rem = i - c * 1672;
        const int r   = rem / 38;
        const int k   = rem - r * 38;
        const int gy = gy0s + r, gx = gx0s + 2 * k;
        float2 v = make_float2(0.f, 0.f);
        if ((unsigned)gy < 256u) {
            const float* src = x + (((size_t)b * 3 + c) * 256 + gy) * 256;
            if (gx >= 0 && gx + 1 < 256) {
                v = *reinterpret_cast<const float2*>(src + gx);
            } else {
                if ((unsigned)gx < 256u)       v.x = src[gx];
                if ((unsigned)(gx + 1) < 256u) v.y = src[gx + 1];
            }
        }
        *reinterpret_cast<float2*>(&sIn[c * 3344 + r * 76 + 2 * k]) = v;
    }
    __syncthreads();

    conv5x5<3, 3, 72, 40, 76, 3344, 76, 3040, true>(sIn, sH1, w1, b1,
                                                    ty * 32 - 4, tx * 64 - 4, tid);
    __syncthreads();
    conv5x5<3, 3, 68, 36, 76, 3040, 76, 2736, true>(sH1, sH2, w2, b2,
                                                    ty * 32 - 2, tx * 64 - 2, tid);
    __syncthreads();
    conv5x5<3, 1, 64, 32, 76, 2736, 64, 2048, false>(sH2, sH3, w3, b3, 0, 0, tid);
    __syncthreads();

    const int wv   = tid >> 6;
    const int lane = tid & 63;
    const int py = wv >> 2, px = wv & 3;
    float s = 0.f;
#pragma unroll
    for (int k = 0; k < 4; ++k) {
        const int idx = lane + k * 64;
        const int r = idx >> 4, cc = idx & 15;
        s += sH3[(py * 16 + r) * 64 + px * 16 + cc];
    }
#pragma unroll
    for (int off = 32; off > 0; off >>= 1) s += __shfl_down(s, off, 64);
    if (lane == 0) {
        const int j = ty * 2 + py, i = tx * 4 + px;
        feat[(size_t)b * 256 + j * 16 + i] = s * (1.f / 256.f);
    }
}

extern "C" void kernel_launch(void* const* d_in, const int* in_sizes, int n_in,
                              void* d_out, int out_size, void* d_ws, size_t ws_size,
                              hipStream_t stream) {
    const float* x   = (const float*)d_in[0];
    const float* w1  = (const float*)d_in[1];
    const float* b1  = (const float*)d_in[2];
    const float* w2  = (const float*)d_in[3];
    const float* b2  = (const float*)d_in[4];
    const float* w3  = (const float*)d_in[5];
    const float* b3  = (const float*)d_in[6];
    const float* wl1 = (const float*)d_in[7];
    const float* bl1 = (const float*)d_in[8];
    const float* wl2 = (const float*)d_in[9];
    const float* bl2 = (const float*)d_in[10];
    float* out  = (float*)d_out;

    const size_t FEAT_B = 256u * 256u * 4u;   // 262144
    const size_t TAB_B  = 4096;
    float* feat = (float*)d_ws;

    if (ws_size >= FEAT_B + TAB_B) {
        u32* wtab = (u32*)((char*)d_ws + FEAT_B);
        pack_weights<<<1, 128, 0, stream>>>(w1, w2, w3, wtab);
        dim3 g(32, 256);
        fused_mfma<<<g, CT, 0, stream>>>(x, b1, b2, b3, wtab, feat);
    } else {
        dim3 g1(32, 256);
        fused_conv_feat<<<g1, NTHREADS, 0, stream>>>(x, w1, b1, w2, b2, w3, b3, feat);
    }
    mlp_head<<<256, 64, 0, stream>>>(feat, wl1, bl1, wl2, bl2, out);
}

// Round 17
// 236.542 us; speedup vs baseline: 1.1717x; 1.0249x over previous
//
#include <hip/hip_runtime.h>
#include <hip/hip_bf16.h>

// Round 17: round-16 EXACTLY, plus __launch_bounds__(256, 4) on fused_mfma.
//  Occupancy is LDS-capped at 4 blocks/CU (40960B x 4 = 160KB) = 4 waves/EU;
//  telling the compiler that 4 waves/EU suffice raises the VGPR budget
//  64 -> 128, removing the register-starvation serialization (live set
//  ~64 floats at VGPR_Count=64 left zero scheduling headroom).
//  Inverse of round-7's mistake: there launch_bounds forced occupancy ABOVE
//  the live set (-> spills); here it aligns registers WITH the LDS cap.

#define CT 256

typedef unsigned int u32;
typedef short bf16x8 __attribute__((ext_vector_type(8)));
typedef float f32x4 __attribute__((ext_vector_type(4)));
typedef unsigned int u32x4 __attribute__((ext_vector_type(4)));

static __device__ __forceinline__ unsigned short f2bf(float f) {
    __hip_bfloat16 h = __float2bfloat16(f);
    return *reinterpret_cast<unsigned short*>(&h);
}
static __device__ __forceinline__ u32 pkbf(float a, float b) {
    __hip_bfloat162 h = __float22bfloat162_rn(make_float2(a, b));
    return *reinterpret_cast<u32*>(&h);
}

#define LSX   88
#define XCS   (44 * LSX)          // 3872
#define LS1   72
#define H1CS  (40 * LS1)          // 2880
#define H2CS  (36 * LS1)          // 2592
// ushort layout: sH1 [0,8640) | pad24 | sX [8664,20280) | pad16
#define SH1_OFF 0
#define SX_OFF  (3 * H1CS + 24)   // 8664 (x2B = 17328, 16B-aligned)
#define LDS_U   20296             // 40592 B -> 4 blocks/CU

// ---------------- weight pack ----------------
__global__ __launch_bounds__(128) void pack_weights(
    const float* __restrict__ w1, const float* __restrict__ w2,
    const float* __restrict__ w3, u32* __restrict__ tab)
{
    const int t = threadIdx.x;
    if (t < 105) {
        const float* w;
        if (t < 45)       w = w1 + t * 5;
        else if (t < 90)  w = w2 + (t - 45) * 5;
        else              w = w3 + (t - 90) * 5;
        tab[t * 3 + 0] = (u32)f2bf(w[0]) | ((u32)f2bf(w[1]) << 16);
        tab[t * 3 + 1] = (u32)f2bf(w[2]) | ((u32)f2bf(w[3]) << 16);
        tab[t * 3 + 2] = (u32)f2bf(w[4]);
    }
}

// ---------------- one fused conv stage (3 oc), LDS -> LDS ----------------
template<int TOFF, int LSI, int INCS, int LSO, int OUTCS, int RB2>
static __device__ __forceinline__ void conv_stage_mfma(
    const unsigned short* __restrict__ sin, unsigned short* __restrict__ sout,
    const u32* __restrict__ tab, const float* __restrict__ bias,
    int gy0m, int gx0m, int lanem, int g, int wid,
    const u32* selA, const u32* selB, bool interior)
{
    f32x4 acc[4][3];
    int rbv[4], cxv[4], rbi[4], baseb[4];
    bool val[4];
#pragma unroll
    for (int i = 0; i < 4; ++i) {
        const int t = wid + 4 * i;
        val[i] = (t < 15);
        const int tc = val[i] ? t : 0;
        cxv[i] = tc % 5;
        rbi[i] = tc / 5;
        rbv[i] = (rbi[i] == 0) ? 0 : (rbi[i] == 1 ? 16 : RB2);
        baseb[i] = ((rbv[i] + lanem) * LSI + 16 * cxv[i] + g * 8) * 2;
    }
#pragma unroll
    for (int oc = 0; oc < 3; ++oc) {
        const float bb = bias[oc];
#pragma unroll
        for (int i = 0; i < 4; ++i) acc[i][oc] = f32x4{bb, bb, bb, bb};
    }

#pragma unroll
    for (int f = 0; f < 15; ++f) {         // f = ic*5 + ky
        const int ic = f / 5, ky = f % 5;
        bf16x8 A[3];
#pragma unroll
        for (int oc = 0; oc < 3; ++oc) {
            const u32* wt = tab + (TOFF + (oc * 3 + ic) * 5 + ky) * 3;
            const u32 w01 = wt[0], w23 = wt[1], w4z = wt[2];
            u32x4 qv;
#pragma unroll
            for (int jj = 0; jj < 4; ++jj)
                qv[jj] = __builtin_amdgcn_perm(
                    __builtin_amdgcn_perm(w23, w01, selA[jj]), w4z, selB[jj]);
            A[oc] = __builtin_bit_cast(bf16x8, qv);
        }
        const int foff = (ic * INCS + ky * LSI) * 2;
#pragma unroll
        for (int i = 0; i < 4; ++i) {
            if (val[i]) {
                const bf16x8 B = *reinterpret_cast<const bf16x8*>(
                    (const char*)sin + baseb[i] + foff);
#pragma unroll
                for (int oc = 0; oc < 3; ++oc)
                    acc[i][oc] = __builtin_amdgcn_mfma_f32_16x16x32_bf16(
                        A[oc], B, acc[i][oc], 0, 0, 0);
            }
        }
    }

    // epilogue: ReLU (+mask if boundary) -> bf16 (cvt_pk) -> LDS
#pragma unroll
    for (int i = 0; i < 4; ++i) {
        if (!val[i]) continue;
        const int colbase = 16 * cxv[i] + 4 * g;
        if (colbase >= LSO) continue;                    // stride overflow
        if (rbi[i] == 2 && lanem < 32 - RB2) continue;   // duplicate rows
        const int row = rbv[i] + lanem;
        const int Y = gy0m + row;
        const bool yok = (unsigned)Y < 256u;
#pragma unroll
        for (int oc = 0; oc < 3; ++oc) {
            float v[4];
#pragma unroll
            for (int p = 0; p < 4; ++p) {
                float rv = fmaxf(acc[i][oc][p], 0.f);
                if (!interior) {
                    const bool ok = yok & ((unsigned)(gx0m + colbase + p) < 256u);
                    rv = ok ? rv : 0.f;
                }
                v[p] = rv;
            }
            *reinterpret_cast<uint2*>(
                sout + oc * OUTCS + row * LSO + colbase) =
                make_uint2(pkbf(v[0], v[1]), pkbf(v[2], v[3]));
        }
    }
}

// ---------------- fused kernel ----------------
__global__ __launch_bounds__(CT, 4) void fused_mfma(
    const float* __restrict__ x,
    const float* __restrict__ b1, const float* __restrict__ b2,
    const float* __restrict__ b3,
    const u32* __restrict__ tab, float* __restrict__ feat)
{
    const int pos = blockIdx.x;            // 0..31
    const int b   = blockIdx.y;            // image
    const int tx = pos & 3, ty = pos >> 2;
    const int tid = threadIdx.x;
    const int lane = tid & 63, wid = tid >> 6;
    const int lanem = lane & 15, g = lane >> 4;

    __shared__ __align__(16) unsigned short lds_u[LDS_U];   // 40592 B
    unsigned short* sH1 = lds_u + SH1_OFF;
    unsigned short* sX  = lds_u + SX_OFF;
    unsigned short* sH2 = sX;               // alias (sX dead after conv1)

    const int gy0 = ty * 32, gx0 = tx * 64;
    const bool interior = (tx >= 1) & (tx <= 2) & (ty >= 1) & (ty <= 6);

    // ---- perm selectors (rounds 10-16 verified) ----
    u32 selA[4], selB[4];
#pragma unroll
    for (int jj = 0; jj < 4; ++jj) {
        u32 a = 0, bs = 0;
#pragma unroll
        for (int byt = 0; byt < 4; ++byt) {
            const int j = 2 * jj + (byt >> 1);
            const int d = g * 8 + j - lanem;
            const int h = byt & 1;
            u32 av, bv;
            if      (d == 0) av = 0 + h;
            else if (d == 1) av = 2 + h;
            else if (d == 2) av = 4 + h;
            else if (d == 3) av = 6 + h;
            else             av = 0;
            if      (d == 4)           bv = 0 + h;   // w4
            else if (d >= 0 && d < 4)  bv = 4 + byt; // keep t1 byte
            else                       bv = 2 + h;   // zero
            a  |= av << (8 * byt);
            bs |= bv << (8 * byt);
        }
        selA[jj] = a; selB[jj] = bs;
    }

    // ---- zero the tail pads ----
    {
        u32* w32 = reinterpret_cast<u32*>(lds_u);
        if (tid < 12)      w32[(3 * H1CS) / 2 + tid] = 0;
        else if (tid < 20) w32[(SX_OFF + 3 * XCS) / 2 + (tid - 12)] = 0;
    }

    // ---- stage x: 44 rows x 88 cols x 3 ch, bf16 ----
    if (interior) {
        for (int p = tid; p < 44 * 44; p += CT) {
            const int r = p / 44;
            const int k = p - r * 44;
            const int gy = gy0 - 6 + r;
            const int gx = gx0 - 6 + 2 * k;
#pragma unroll
            for (int c = 0; c < 3; ++c) {
                const float2 v = *reinterpret_cast<const float2*>(
                    x + (((size_t)b * 3 + c) * 256 + gy) * 256 + gx);
                *reinterpret_cast<u32*>(&sX[c * XCS + r * LSX + 2 * k]) =
                    pkbf(v.x, v.y);
            }
        }
    } else {
        for (int p = tid; p < 44 * 44; p += CT) {
            const int r = p / 44;
            const int k = p - r * 44;
            const int gy = gy0 - 6 + r;
            const int gx = gx0 - 6 + 2 * k;
            const bool yok  = ((unsigned)gy < 256u) & (k < 38);
            const bool full = yok & (gx >= 0) & (gx + 1 < 256);
#pragma unroll
            for (int c = 0; c < 3; ++c) {
                u32 packed = 0;
                if (yok) {
                    const float* src = x + (((size_t)b * 3 + c) * 256 + gy) * 256;
                    float vx = 0.f, vy = 0.f;
                    if (full) {
                        const float2 v = *reinterpret_cast<const float2*>(src + gx);
                        vx = v.x; vy = v.y;
                    } else {
                        if ((unsigned)gx < 256u)       vx = src[gx];
                        if ((unsigned)(gx + 1) < 256u) vy = src[gx + 1];
                    }
                    packed = pkbf(vx, vy);
                }
                *reinterpret_cast<u32*>(&sX[c * XCS + r * LSX + 2 * k]) = packed;
            }
        }
    }
    __syncthreads();

    // ---- conv1: sX(88) -> sH1(72), origin (gy0-4, gx0-4) ----
    conv_stage_mfma<0, LSX, XCS, LS1, H1CS, 24>(sX, sH1, tab, b1,
        gy0 - 4, gx0 - 4, lanem, g, wid, selA, selB, interior);
    __syncthreads();

    // ---- conv2: sH1(72) -> sH2(72), origin (gy0-2, gx0-2) ----
    conv_stage_mfma<45, LS1, H1CS, LS1, H2CS, 20>(sH1, sH2, tab, b2,
        gy0 - 2, gx0 - 2, lanem, g, wid, selA, selB, interior);
    __syncthreads();

    // ---- conv3 + patch-mean: sH2 -> feat; tiles (cx=wid, rb in {0,16}) ----
    {
        const float bb = b3[0];
        f32x4 a3[2] = {f32x4{bb, bb, bb, bb}, f32x4{bb, bb, bb, bb}};
        int base_s[2];
#pragma unroll
        for (int s = 0; s < 2; ++s)
            base_s[s] = ((s * 16 + lanem) * LS1 + 16 * wid + g * 8) * 2;

#pragma unroll
        for (int f = 0; f < 15; ++f) {
            const int ic = f / 5, ky = f % 5;
            const u32* wt = tab + (90 + f) * 3;
            const u32 w01 = wt[0], w23 = wt[1], w4z = wt[2];
            u32x4 qv;
#pragma unroll
            for (int jj = 0; jj < 4; ++jj)
                qv[jj] = __builtin_amdgcn_perm(
                    __builtin_amdgcn_perm(w23, w01, selA[jj]), w4z, selB[jj]);
            const bf16x8 A = __builtin_bit_cast(bf16x8, qv);
            const int foff = (ic * H2CS + ky * LS1) * 2;
#pragma unroll
            for (int s = 0; s < 2; ++s) {
                const bf16x8 B = *reinterpret_cast<const bf16x8*>(
                    (const char*)sH2 + base_s[s] + foff);
                a3[s] = __builtin_amdgcn_mfma_f32_16x16x32_bf16(A, B, a3[s], 0, 0, 0);
            }
        }
#pragma unroll
        for (int s = 0; s < 2; ++s) {
            float sum = fmaxf(a3[s][0], 0.f) + fmaxf(a3[s][1], 0.f)
                      + fmaxf(a3[s][2], 0.f) + fmaxf(a3[s][3], 0.f);
            sum += __shfl_xor(sum, 1, 64);
            sum += __shfl_xor(sum, 2, 64);
            sum += __shfl_xor(sum, 4, 64);
            sum += __shfl_xor(sum, 8, 64);
            sum += __shfl_xor(sum, 16, 64);
            sum += __shfl_xor(sum, 32, 64);
            if (lane == 0) {
                const int j = ty * 2 + s, i2 = tx * 4 + wid;
                feat[(size_t)b * 256 + j * 16 + i2] = sum * (1.f / 256.f);
            }
        }
    }
}

// ---------------- MLP head ----------------
__global__ __launch_bounds__(64) void mlp_head(
    const float* __restrict__ feat,
    const float* __restrict__ wl1, const float* __restrict__ bl1,
    const float* __restrict__ wl2, const float* __restrict__ bl2,
    float* __restrict__ out)
{
    const int b = blockIdx.x;
    const int t = threadIdx.x;

    __shared__ float sF[256];
    __shared__ float sE[64];
    __shared__ float sL[8];
    __shared__ float sXx[8];

    for (int i = t; i < 256; i += 64) sF[i] = feat[(size_t)b * 256 + i];
    __syncthreads();

    float acc = bl1[t];
    for (int k = 0; k < 256; ++k) acc = fmaf(sF[k], wl1[t * 256 + k], acc);
    sE[t] = acc;
    __syncthreads();

    if (t < 8) {
        float l = bl2[t];
#pragma unroll
        for (int k = 0; k < 64; ++k) l = fmaf(sE[k], wl2[t * 64 + k], l);
        sL[t] = l;
    }
    __syncthreads();

    if (t < 8) {
        float m = sL[0];
#pragma unroll
        for (int k = 1; k < 8; ++k) m = fmaxf(m, sL[k]);
        sXx[t] = __expf(sL[t] - m);
    }
    __syncthreads();

    if (t < 8) {
        float sum = 0.f;
#pragma unroll
        for (int k = 0; k < 8; ++k) sum += sXx[k];
        out[(size_t)b * 8 + t] = sXx[t] / sum;
    }
}

// ---------------- scalar fused fallback (round-3) ----------------
#define NTHREADS 512

template<int ICn, int OCn, int OW, int OH, int IS, int ICSZ, int OS, int OCSZ, bool MASK>
__device__ __forceinline__ void conv5x5(
    const float* __restrict__ sin, float* __restrict__ sout,
    const float* __restrict__ w, const float* __restrict__ bias,
    int gy0, int gx0, int tid)
{
    constexpr int QX = OW / 4;
    constexpr int RY = OH / 2;
    constexpr int TASKS = QX * RY;
    if (tid < TASKS) {
        const int ry = tid / QX;
        const int qx = tid - ry * QX;
        const int y0 = ry * 2, x0 = qx * 4;
        float acc[2][OCn][4];
#pragma unroll
        for (int c = 0; c < OCn; ++c) {
            const float bb = bias[c];
#pragma unroll
            for (int p = 0; p < 4; ++p) { acc[0][c][p] = bb; acc[1][c][p] = bb; }
        }
#pragma unroll
        for (int ic = 0; ic < ICn; ++ic) {
            const float* base = sin + ic * ICSZ + y0 * IS + x0;
#pragma unroll
            for (int r = 0; r < 6; ++r) {
                const float4 a4 = *reinterpret_cast<const float4*>(base + r * IS);
                const float4 b4 = *reinterpret_cast<const float4*>(base + r * IS + 4);
                const float v[8] = {a4.x, a4.y, a4.z, a4.w, b4.x, b4.y, b4.z, b4.w};
#pragma unroll
                for (int kx = 0; kx < 5; ++kx)
#pragma unroll
                    for (int c = 0; c < OCn; ++c) {
                        if (r < 5) {
                            const float wv = w[((c * ICn + ic) * 5 + r) * 5 + kx];
#pragma unroll
                            for (int p = 0; p < 4; ++p)
                                acc[0][c][p] = fmaf(v[p + kx], wv, acc[0][c][p]);
                        }
                        if (r >= 1) {
                            const float wv = w[((c * ICn + ic) * 5 + (r - 1)) * 5 + kx];
#pragma unroll
                            for (int p = 0; p < 4; ++p)
                                acc[1][c][p] = fmaf(v[p + kx], wv, acc[1][c][p]);
                        }
                    }
            }
        }
#pragma unroll
        for (int rr = 0; rr < 2; ++rr) {
            const int gy = gy0 + y0 + rr;
#pragma unroll
            for (int c = 0; c < OCn; ++c) {
                float o[4];
#pragma unroll
                for (int p = 0; p < 4; ++p) {
                    float rv = fmaxf(acc[rr][c][p], 0.f);
                    if (MASK) {
                        const int gx = gx0 + x0 + p;
                        const bool ok = ((unsigned)gy < 256u) & ((unsigned)gx < 256u);
                        rv = ok ? rv : 0.f;
                    }
                    o[p] = rv;
                }
                *reinterpret_cast<float4*>(&sout[c * OCSZ + (y0 + rr) * OS + x0]) =
                    make_float4(o[0], o[1], o[2], o[3]);
            }
        }
    }
}

__global__ __launch_bounds__(NTHREADS) void fused_conv_feat(
    const float* __restrict__ x,
    const float* __restrict__ w1, const float* __restrict__ b1,
    const float* __restrict__ w2, const float* __restrict__ b2,
    const float* __restrict__ w3, const float* __restrict__ b3,
    float* __restrict__ feat)
{
    const int tile = blockIdx.x;
    const int b    = blockIdx.y;
    const int tx   = tile & 3, ty = tile >> 2;
    const int tid  = threadIdx.x;

    __shared__ __align__(16) float lds[10032 + 9120];
    float* sIn = lds;
    float* sH1 = lds + 10032;
    float* sH2 = lds;
    float* sH3 = lds + 10032;

    const int gy0s = ty * 32 - 6, gx0s = tx * 64 - 6;
    for (int i = tid; i < 3 * 44 * 38; i += NTHREADS) {
        const int c   = i / 1672;
        const int rem = i - c * 1672;
        const int r   = rem / 38;
        const int k   = rem - r * 38;
        const int gy = gy0s + r, gx = gx0s + 2 * k;
        float2 v = make_float2(0.f, 0.f);
        if ((unsigned)gy < 256u) {
            const float* src = x + (((size_t)b * 3 + c) * 256 + gy) * 256;
            if (gx >= 0 && gx + 1 < 256) {
                v = *reinterpret_cast<const float2*>(src + gx);
            } else {
                if ((unsigned)gx < 256u)       v.x = src[gx];
                if ((unsigned)(gx + 1) < 256u) v.y = src[gx + 1];
            }
        }
        *reinterpret_cast<float2*>(&sIn[c * 3344 + r * 76 + 2 * k]) = v;
    }
    __syncthreads();

    conv5x5<3, 3, 72, 40, 76, 3344, 76, 3040, true>(sIn, sH1, w1, b1,
                                                    ty * 32 - 4, tx * 64 - 4, tid);
    __syncthreads();
    conv5x5<3, 3, 68, 36, 76, 3040, 76, 2736, true>(sH1, sH2, w2, b2,
                                                    ty * 32 - 2, tx * 64 - 2, tid);
    __syncthreads();
    conv5x5<3, 1, 64, 32, 76, 2736, 64, 2048, false>(sH2, sH3, w3, b3, 0, 0, tid);
    __syncthreads();

    const int wv   = tid >> 6;
    const int lane = tid & 63;
    const int py = wv >> 2, px = wv & 3;
    float s = 0.f;
#pragma unroll
    for (int k = 0; k < 4; ++k) {
        const int idx = lane + k * 64;
        const int r = idx >> 4, cc = idx & 15;
        s += sH3[(py * 16 + r) * 64 + px * 16 + cc];
    }
#pragma unroll
    for (int off = 32; off > 0; off >>= 1) s += __shfl_down(s, off, 64);
    if (lane == 0) {
        const int j = ty * 2 + py, i = tx * 4 + px;
        feat[(size_t)b * 256 + j * 16 + i] = s * (1.f / 256.f);
    }
}

extern "C" void kernel_launch(void* const* d_in, const int* in_sizes, int n_in,
                              void* d_out, int out_size, void* d_ws, size_t ws_size,
                              hipStream_t stream) {
    const float* x   = (const float*)d_in[0];
    const float* w1  = (const float*)d_in[1];
    const float* b1  = (const float*)d_in[2];
    const float* w2  = (const float*)d_in[3];
    const float* b2  = (const float*)d_in[4];
    const float* w3  = (const float*)d_in[5];
    const float* b3  = (const float*)d_in[6];
    const float* wl1 = (const float*)d_in[7];
    const float* bl1 = (const float*)d_in[8];
    const float* wl2 = (const float*)d_in[9];
    const float* bl2 = (const float*)d_in[10];
    float* out  = (float*)d_out;

    const size_t FEAT_B = 256u * 256u * 4u;   // 262144
    const size_t TAB_B  = 4096;
    float* feat = (float*)d_ws;

    if (ws_size >= FEAT_B + TAB_B) {
        u32* wtab = (u32*)((char*)d_ws + FEAT_B);
        pack_weights<<<1, 128, 0, stream>>>(w1, w2, w3, wtab);
        dim3 g(32, 256);
        fused_mfma<<<g, CT, 0, stream>>>(x, b1, b2, b3, wtab, feat);
    } else {
        dim3 g1(32, 256);
        fused_conv_feat<<<g1, NTHREADS, 0, stream>>>(x, w1, b1, w2, b2, w3, b3, feat);
    }
    mlp_head<<<256, 64, 0, stream>>>(feat, wl1, bl1, wl2, bl2, out);
}